// Round 6
// baseline (249.489 us; speedup 1.0000x reference)
//
#include <hip/hip_runtime.h>
#include <hip/hip_bf16.h>

// GCN 2-layer, N=20000, F_IN=512, H=256, C=40, E=640000, fp32 in/out.
// Algebra: fold dinv into GEMM epilogues so aggregations are PLAIN SUMS:
//   h1s = bf16(dinv_i * (x@W1))           (gemm1)
//   hrb = relu(dinv_i * (sum_nbr h1s + h1s_i) + b1)        (agg1, unweighted)
//   h2b = bf16(dinv_i * (hrb@W2))         (gemm2)
//   out = dinv_i * (sum_nbr h2b + h2b_i) + b2              (agg2, unweighted)
// Edge record = src index only (4B). Row N of h1s/h2b is zeroed (slack target).

#define N_NODES 20000
#define F_IN    512
#define H_DIM   256
#define C_DIM   40
#define C_PAD   64
#define E_EDGES 640000
#define NBLK    80
#define CHUNK   250
#define EB      2500          // count blocks (E/256)
#define WB      576           // wt blocks ((512*256+256*64)/256)

typedef __attribute__((ext_vector_type(8))) short short8;
typedef __attribute__((ext_vector_type(4))) float floatx4;

__device__ __forceinline__ float bf2f(unsigned short u) {
    union { unsigned int i; float f; } v;
    v.i = ((unsigned int)u) << 16;
    return v.f;
}
__device__ __forceinline__ unsigned short f2bf(float f) {
    unsigned int u = __float_as_uint(f);
    unsigned int r = (u + 0x7fffu + ((u >> 16) & 1u)) >> 16;   // RNE
    return (unsigned short)r;
}
__device__ __forceinline__ float lo16(unsigned int u) { return __uint_as_float(u << 16); }
__device__ __forceinline__ float hi16(unsigned int u) { return __uint_as_float(u & 0xffff0000u); }
__device__ __forceinline__ unsigned int pack2(float a, float b) {
    return (unsigned int)f2bf(a) | ((unsigned int)f2bf(b) << 16);
}

// ---------------- prep: count atomics + weight transpose/cast + zero rows ----------------

__global__ __launch_bounds__(256) void prep_kernel(const int* __restrict__ dst,
                                                   int* __restrict__ cnt,
                                                   const float* __restrict__ W1,
                                                   const float* __restrict__ W2,
                                                   unsigned short* __restrict__ w1t,
                                                   unsigned short* __restrict__ w2t,
                                                   unsigned short* __restrict__ h1s,
                                                   unsigned short* __restrict__ h2b) {
    const int b = blockIdx.x, t = threadIdx.x;
    if (b < EB) {
        atomicAdd(&cnt[dst[b * 256 + t]], 1);
    } else if (b < EB + WB) {
        int idx = (b - EB) * 256 + t;
        if (idx < F_IN * H_DIM) {
            int n = idx >> 9, k = idx & 511;
            w1t[idx] = f2bf(W1[k * H_DIM + n]);
        } else {
            int id2 = idx - F_IN * H_DIM;
            int n = id2 >> 8, k = id2 & 255;
            w2t[id2] = (n < C_DIM) ? f2bf(W2[k * C_DIM + n]) : (unsigned short)0;
        }
    } else {
        h1s[(size_t)N_NODES * H_DIM + t] = 0;        // zero row N (slack gather target)
        if (t < C_PAD) h2b[(size_t)N_NODES * C_PAD + t] = 0;
    }
}

// ---------------- rowptr/cursor/dinv: self-sufficient per-block scan ----------------

__global__ __launch_bounds__(256) void rowptr_kernel(const int* __restrict__ cnt,
                                                     int* __restrict__ rowptr,
                                                     int* __restrict__ cursor,
                                                     float* __restrict__ dinv) {
    __shared__ int red[256];
    __shared__ int sc[256];
    const int t = threadIdx.x, j = blockIdx.x;
    int s = 0;
    for (int i = t; i < j * CHUNK; i += 256) s += cnt[i];
    red[t] = s;
    __syncthreads();
    for (int st = 128; st > 0; st >>= 1) {
        if (t < st) red[t] += red[t + st];
        __syncthreads();
    }
    const int boff = red[0];
    const int c = (t < CHUNK) ? cnt[j * CHUNK + t] : 0;
    sc[t] = c;
    __syncthreads();
    for (int st = 1; st < 256; st <<= 1) {       // Hillis-Steele inclusive
        int add = (t >= st) ? sc[t - st] : 0;
        __syncthreads();
        sc[t] += add;
        __syncthreads();
    }
    if (t < CHUNK) {
        int idx = j * CHUNK + t;
        int rp = boff + sc[t] - c;               // exclusive
        rowptr[idx] = rp;
        cursor[idx] = rp;
        dinv[idx] = rsqrtf((float)c + 1.0f);
    }
    if (j == NBLK - 1 && t == 0) rowptr[N_NODES] = E_EDGES;
}

// cursor pre-seeded with rowptr -> atomicAdd returns absolute slot; 4B record
__global__ void fill_kernel(const int* __restrict__ src, const int* __restrict__ dst,
                            int* __restrict__ cursor, int* __restrict__ esrc) {
    int e = blockIdx.x * blockDim.x + threadIdx.x;
    int s = src[e];
    int d = dst[e];
    esrc[atomicAdd(&cursor[d], 1)] = s;
}

// ---------------- gemm1: h1s[M,256] = bf16( dinv_row * (x[M,512] @ W1) ) ----------------
// Block = 4 waves, tile 64x256. Wave w: rows [w*16,w*16+16), 16 n-tiles.

__global__ __launch_bounds__(256) void gemm1_kernel(const float* __restrict__ A,
                                                    const unsigned short* __restrict__ BT,
                                                    const float* __restrict__ dinv,
                                                    unsigned short* __restrict__ Cb) {
    __shared__ short As[64 * 40];
    __shared__ short Bs[256 * 40];
    const int tid = threadIdx.x;
    const int w = tid >> 6;
    const int lane = tid & 63;
    const int lq = lane >> 4;
    const int lm = lane & 15;
    const int row0 = blockIdx.x * 64;
    const int sr = tid >> 2;        // 0..63
    const int sc = (tid & 3) * 8;   // 0,8,16,24

    floatx4 acc[16];
#pragma unroll
    for (int t = 0; t < 16; ++t) acc[t] = (floatx4){0.f, 0.f, 0.f, 0.f};

    for (int k0 = 0; k0 < F_IN; k0 += 32) {
        {
            const int gr = row0 + sr;
            short8 av = (short8){0,0,0,0,0,0,0,0};
            if (gr < N_NODES) {
                const float* p = A + (size_t)gr * F_IN + k0 + sc;
                float4 a0 = *(const float4*)p;
                float4 a1 = *(const float4*)(p + 4);
                av[0] = (short)f2bf(a0.x); av[1] = (short)f2bf(a0.y);
                av[2] = (short)f2bf(a0.z); av[3] = (short)f2bf(a0.w);
                av[4] = (short)f2bf(a1.x); av[5] = (short)f2bf(a1.y);
                av[6] = (short)f2bf(a1.z); av[7] = (short)f2bf(a1.w);
            }
            *(short8*)&As[sr * 40 + sc] = av;
        }
#pragma unroll
        for (int j = 0; j < 4; ++j) {
            int row = j * 64 + sr;
            *(short8*)&Bs[row * 40 + sc] = *(const short8*)&BT[(size_t)row * F_IN + k0 + sc];
        }
        __syncthreads();
        short8 af = *(const short8*)&As[(w * 16 + lm) * 40 + lq * 8];
#pragma unroll
        for (int t = 0; t < 16; ++t) {
            short8 bf = *(const short8*)&Bs[(t * 16 + lm) * 40 + lq * 8];
            acc[t] = __builtin_amdgcn_mfma_f32_16x16x32_bf16(af, bf, acc[t], 0, 0, 0);
        }
        __syncthreads();
    }
    float dv[4];
#pragma unroll
    for (int r = 0; r < 4; ++r) {
        int row = row0 + w * 16 + lq * 4 + r;
        dv[r] = (row < N_NODES) ? dinv[row] : 0.f;
    }
#pragma unroll
    for (int t = 0; t < 16; ++t) {
#pragma unroll
        for (int r = 0; r < 4; ++r) {
            int row = row0 + w * 16 + lq * 4 + r;
            int col = t * 16 + lm;
            if (row < N_NODES) Cb[(size_t)row * H_DIM + col] = f2bf(acc[t][r] * dv[r]);
        }
    }
}

// ---------------- gemm2: h2b[M,64] = bf16( dinv_row * (hrb[M,256] @ W2) ) ----------------

__global__ __launch_bounds__(256) void gemm2_kernel(const unsigned short* __restrict__ Ab,
                                                    const unsigned short* __restrict__ BT,
                                                    const float* __restrict__ dinv,
                                                    unsigned short* __restrict__ Cb) {
    __shared__ short As[64 * 40];
    __shared__ short Bs[64 * 40];
    const int tid = threadIdx.x;
    const int w = tid >> 6;
    const int lane = tid & 63;
    const int lq = lane >> 4;
    const int lm = lane & 15;
    const int row0 = blockIdx.x * 64;
    const int sr = tid >> 2;
    const int sc = (tid & 3) * 8;

    floatx4 acc[4];
#pragma unroll
    for (int t = 0; t < 4; ++t) acc[t] = (floatx4){0.f, 0.f, 0.f, 0.f};

    for (int k0 = 0; k0 < H_DIM; k0 += 32) {
        {
            const int gr = row0 + sr;
            short8 av = (short8){0,0,0,0,0,0,0,0};
            if (gr < N_NODES)
                av = *(const short8*)&Ab[(size_t)gr * H_DIM + k0 + sc];
            *(short8*)&As[sr * 40 + sc] = av;
            *(short8*)&Bs[sr * 40 + sc] = *(const short8*)&BT[(size_t)sr * H_DIM + k0 + sc];
        }
        __syncthreads();
        short8 af = *(const short8*)&As[(w * 16 + lm) * 40 + lq * 8];
#pragma unroll
        for (int t = 0; t < 4; ++t) {
            short8 bf = *(const short8*)&Bs[(t * 16 + lm) * 40 + lq * 8];
            acc[t] = __builtin_amdgcn_mfma_f32_16x16x32_bf16(af, bf, acc[t], 0, 0, 0);
        }
        __syncthreads();
    }
    float dv[4];
#pragma unroll
    for (int r = 0; r < 4; ++r) {
        int row = row0 + w * 16 + lq * 4 + r;
        dv[r] = (row < N_NODES) ? dinv[row] : 0.f;
    }
#pragma unroll
    for (int t = 0; t < 4; ++t) {
#pragma unroll
        for (int r = 0; r < 4; ++r) {
            int row = row0 + w * 16 + lq * 4 + r;
            int col = t * 16 + lm;
            if (row < N_NODES) Cb[(size_t)row * C_PAD + col] = f2bf(acc[t][r] * dv[r]);
        }
    }
}

// ---------------- agg1: quarter-sliced plain-sum gather, 16 edges/iter ----------------
// Block b: quarter q=b&3 (XCD slicing), node i=(b>>2)*4+wave. Wave: 8 groups x
// 8 lanes; group g = edge slot; lane covers 8 features (16B) -> 128B line/edge.
// Two independent 8-edge gather chains per iter; esrc prefetched 2 slots ahead.

__global__ __launch_bounds__(256) void agg1_kernel(const unsigned short* __restrict__ h1s,
                                                   const int* __restrict__ rowptr,
                                                   const int* __restrict__ esrc,
                                                   const float* __restrict__ dinv,
                                                   const float* __restrict__ b1,
                                                   unsigned short* __restrict__ hrb) {
    const int b = blockIdx.x;
    const int q = b & 3;
    const int w = threadIdx.x >> 6;
    const int lane = threadIdx.x & 63;
    const int g = lane >> 3;          // edge slot 0..7
    const int lm = lane & 7;          // feature octet
    const int i = (b >> 2) * 4 + w;   // node
    const int fbase = q * 64 + lm * 8;
    const unsigned short* __restrict__ hp = h1s + fbase;
    const int rb = rowptr[i], re = rowptr[i + 1];
    float a0[8] = {0,0,0,0,0,0,0,0}, a1[8] = {0,0,0,0,0,0,0,0};
    int e0 = esrc[rb + g];
    int e1 = esrc[rb + 8 + g];
    for (int k = rb; k < re; k += 16) {
        int p0 = esrc[k + 16 + g];            // slack-padded (E+32), safe
        int p1 = esrc[k + 24 + g];
        int s0 = (k + g) < re ? e0 : N_NODES;
        int s1 = (k + 8 + g) < re ? e1 : N_NODES;
        uint4 v0 = *(const uint4*)(hp + ((size_t)s0 << 8));
        uint4 v1 = *(const uint4*)(hp + ((size_t)s1 << 8));
        a0[0] += lo16(v0.x); a0[1] += hi16(v0.x);
        a0[2] += lo16(v0.y); a0[3] += hi16(v0.y);
        a0[4] += lo16(v0.z); a0[5] += hi16(v0.z);
        a0[6] += lo16(v0.w); a0[7] += hi16(v0.w);
        a1[0] += lo16(v1.x); a1[1] += hi16(v1.x);
        a1[2] += lo16(v1.y); a1[3] += hi16(v1.y);
        a1[4] += lo16(v1.z); a1[5] += hi16(v1.z);
        a1[6] += lo16(v1.w); a1[7] += hi16(v1.w);
        e0 = p0; e1 = p1;
    }
    float r[8];
#pragma unroll
    for (int j = 0; j < 8; ++j) {
        float v = a0[j] + a1[j];
        v += __shfl_xor(v, 8, 64);
        v += __shfl_xor(v, 16, 64);
        v += __shfl_xor(v, 32, 64);
        r[j] = v;
    }
    if (lane < 8) {
        uint4 sv = *(const uint4*)(hp + ((size_t)i << 8));    // self (lm == lane)
        r[0] += lo16(sv.x); r[1] += hi16(sv.x);
        r[2] += lo16(sv.y); r[3] += hi16(sv.y);
        r[4] += lo16(sv.z); r[5] += hi16(sv.z);
        r[6] += lo16(sv.w); r[7] += hi16(sv.w);
        const float di = dinv[i];
        float4 bb0 = *(const float4*)&b1[fbase];
        float4 bb1 = *(const float4*)&b1[fbase + 4];
        float bv[8] = {bb0.x, bb0.y, bb0.z, bb0.w, bb1.x, bb1.y, bb1.z, bb1.w};
        float o[8];
#pragma unroll
        for (int j = 0; j < 8; ++j) o[j] = fmaxf(fmaf(di, r[j], bv[j]), 0.f);
        uint4 ov = make_uint4(pack2(o[0], o[1]), pack2(o[2], o[3]),
                              pack2(o[4], o[5]), pack2(o[6], o[7]));
        *(uint4*)&hrb[(size_t)i * H_DIM + fbase] = ov;
    }
}

// ---------------- agg2: wave/node plain-sum gather of h2b, 16 edges/iter ----------------

__global__ __launch_bounds__(256) void agg2_kernel(const unsigned short* __restrict__ h2b,
                                                   const int* __restrict__ rowptr,
                                                   const int* __restrict__ esrc,
                                                   const float* __restrict__ dinv,
                                                   const float* __restrict__ b2,
                                                   float* __restrict__ out) {
    const int i = (blockIdx.x * 256 + threadIdx.x) >> 6;   // node
    const int lane = threadIdx.x & 63;
    const int g = lane >> 3;          // edge slot 0..7
    const int lm = lane & 7;          // col octet
    const int c0 = lm * 8;
    const unsigned short* __restrict__ hp = h2b + c0;
    const int rb = rowptr[i], re = rowptr[i + 1];
    float a0[8] = {0,0,0,0,0,0,0,0}, a1[8] = {0,0,0,0,0,0,0,0};
    int e0 = esrc[rb + g];
    int e1 = esrc[rb + 8 + g];
    for (int k = rb; k < re; k += 16) {
        int p0 = esrc[k + 16 + g];
        int p1 = esrc[k + 24 + g];
        int s0 = (k + g) < re ? e0 : N_NODES;
        int s1 = (k + 8 + g) < re ? e1 : N_NODES;
        uint4 v0 = *(const uint4*)(hp + ((size_t)s0 << 6));
        uint4 v1 = *(const uint4*)(hp + ((size_t)s1 << 6));
        a0[0] += lo16(v0.x); a0[1] += hi16(v0.x);
        a0[2] += lo16(v0.y); a0[3] += hi16(v0.y);
        a0[4] += lo16(v0.z); a0[5] += hi16(v0.z);
        a0[6] += lo16(v0.w); a0[7] += hi16(v0.w);
        a1[0] += lo16(v1.x); a1[1] += hi16(v1.x);
        a1[2] += lo16(v1.y); a1[3] += hi16(v1.y);
        a1[4] += lo16(v1.z); a1[5] += hi16(v1.z);
        a1[6] += lo16(v1.w); a1[7] += hi16(v1.w);
        e0 = p0; e1 = p1;
    }
    float r[8];
#pragma unroll
    for (int j = 0; j < 8; ++j) {
        float v = a0[j] + a1[j];
        v += __shfl_xor(v, 8, 64);
        v += __shfl_xor(v, 16, 64);
        v += __shfl_xor(v, 32, 64);
        r[j] = v;
    }
    if (lane < 5) {                   // lm 0..4 -> cols 0..39
        uint4 sv = *(const uint4*)(hp + ((size_t)i << 6));
        r[0] += lo16(sv.x); r[1] += hi16(sv.x);
        r[2] += lo16(sv.y); r[3] += hi16(sv.y);
        r[4] += lo16(sv.z); r[5] += hi16(sv.z);
        r[6] += lo16(sv.w); r[7] += hi16(sv.w);
        const float di = dinv[i];
        float4 bb0 = *(const float4*)&b2[c0];
        float4 bb1 = *(const float4*)&b2[c0 + 4];
        float* op = &out[(size_t)i * C_DIM + c0];
        *(float4*)op = make_float4(fmaf(di, r[0], bb0.x), fmaf(di, r[1], bb0.y),
                                   fmaf(di, r[2], bb0.z), fmaf(di, r[3], bb0.w));
        *(float4*)(op + 4) = make_float4(fmaf(di, r[4], bb1.x), fmaf(di, r[5], bb1.y),
                                         fmaf(di, r[6], bb1.z), fmaf(di, r[7], bb1.w));
    }
}

// ---------------- launch ----------------

extern "C" void kernel_launch(void* const* d_in, const int* in_sizes, int n_in,
                              void* d_out, int out_size, void* d_ws, size_t ws_size,
                              hipStream_t stream) {
    const float* x   = (const float*)d_in[0];
    const int*   ei  = (const int*)d_in[1];
    const float* W1  = (const float*)d_in[2];
    const float* b1  = (const float*)d_in[3];
    const float* W2  = (const float*)d_in[4];
    const float* b2  = (const float*)d_in[5];
    float* out = (float*)d_out;

    const int* src = ei;            // edge_index[0]
    const int* dst = ei + E_EDGES;  // edge_index[1]

    // workspace layout, 128B-aligned. Total ~26.2 MB.
    char* ws = (char*)d_ws;
    int*            cnt    = (int*)(ws + 0);            //   80000 B
    float*          dinv   = (float*)(ws + 80128);      //   80000 B
    int*            rowptr = (int*)(ws + 160128);       //   80004 B
    int*            cursor = (int*)(ws + 240256);       //   80000 B
    int*            esrc   = (int*)(ws + 320256);       // (E+32)*4 = 2560128 B
    unsigned short* w1t    = (unsigned short*)(ws + 2880384);   //   262144 B
    unsigned short* w2t    = (unsigned short*)(ws + 3142528);   //    32768 B
    unsigned short* h1s    = (unsigned short*)(ws + 3175296);   // (N+1)*256*2 = 10240512 B
    unsigned short* hrb    = (unsigned short*)(ws + 13415808);  // N*256*2   = 10240000 B
    unsigned short* h2b    = (unsigned short*)(ws + 23655808);  // (N+1)*64*2 = 2560128 B

    hipMemsetAsync(cnt, 0, N_NODES * sizeof(int), stream);

    prep_kernel<<<EB + WB + 1, 256, 0, stream>>>(dst, cnt, W1, W2, w1t, w2t, h1s, h2b);
    rowptr_kernel<<<NBLK, 256, 0, stream>>>(cnt, rowptr, cursor, dinv);
    fill_kernel<<<EB, 256, 0, stream>>>(src, dst, cursor, esrc);

    gemm1_kernel<<<(N_NODES + 63) / 64, 256, 0, stream>>>(x, w1t, dinv, h1s);

    agg1_kernel<<<N_NODES, 256, 0, stream>>>(h1s, rowptr, esrc, dinv, b1, hrb);

    gemm2_kernel<<<(N_NODES + 63) / 64, 256, 0, stream>>>(hrb, w2t, dinv, h2b);

    agg2_kernel<<<N_NODES / 4, 256, 0, stream>>>(h2b, rowptr, esrc, dinv, b2, out);
}

// Round 7
// 246.172 us; speedup vs baseline: 1.0135x; 1.0135x over previous
//
#include <hip/hip_runtime.h>
#include <hip/hip_bf16.h>

// GCN 2-layer, N=20000, F_IN=512, H=256, C=40, E=640000, fp32 in/out.
// Algebra: dinv folded into GEMM epilogues -> aggregations are PLAIN SUMS:
//   h1s = bf16(dinv_i * (x@W1))                       (gemm1, 128x128 MFMA tile)
//   hrb = relu(dinv_i * (sum_nbr h1s + h1s_i) + b1)   (agg1, unweighted, 32 edges/iter)
//   h2b = bf16(dinv_i * (hrb@W2))                     (gemm2)
//   out = dinv_i * (sum_nbr h2b + h2b_i) + b2         (agg2, unweighted)
// Edge record = src index (4B). Row N of h1s/h2b zeroed = OOB gather target.

#define N_NODES 20000
#define F_IN    512
#define H_DIM   256
#define C_DIM   40
#define C_PAD   64
#define E_EDGES 640000
#define NBLK    80
#define CHUNK   250
#define EB      2500          // count blocks (E/256)
#define WB      576           // wt blocks ((512*256+256*64)/256)

typedef __attribute__((ext_vector_type(8))) short short8;
typedef __attribute__((ext_vector_type(4))) float floatx4;

__device__ __forceinline__ float bf2f(unsigned short u) {
    union { unsigned int i; float f; } v;
    v.i = ((unsigned int)u) << 16;
    return v.f;
}
__device__ __forceinline__ unsigned short f2bf(float f) {
    unsigned int u = __float_as_uint(f);
    unsigned int r = (u + 0x7fffu + ((u >> 16) & 1u)) >> 16;   // RNE
    return (unsigned short)r;
}
__device__ __forceinline__ float lo16(unsigned int u) { return __uint_as_float(u << 16); }
__device__ __forceinline__ float hi16(unsigned int u) { return __uint_as_float(u & 0xffff0000u); }
__device__ __forceinline__ unsigned int pack2(float a, float b) {
    return (unsigned int)f2bf(a) | ((unsigned int)f2bf(b) << 16);
}
#define ACC8(A, v) do { \
    A[0] += lo16((v).x); A[1] += hi16((v).x); \
    A[2] += lo16((v).y); A[3] += hi16((v).y); \
    A[4] += lo16((v).z); A[5] += hi16((v).z); \
    A[6] += lo16((v).w); A[7] += hi16((v).w); } while (0)

// ---------------- prep: count atomics + weight transpose/cast + zero rows ----------------

__global__ __launch_bounds__(256) void prep_kernel(const int* __restrict__ dst,
                                                   int* __restrict__ cnt,
                                                   const float* __restrict__ W1,
                                                   const float* __restrict__ W2,
                                                   unsigned short* __restrict__ w1t,
                                                   unsigned short* __restrict__ w2t,
                                                   unsigned short* __restrict__ h1s,
                                                   unsigned short* __restrict__ h2b) {
    const int b = blockIdx.x, t = threadIdx.x;
    if (b < EB) {
        atomicAdd(&cnt[dst[b * 256 + t]], 1);
    } else if (b < EB + WB) {
        int idx = (b - EB) * 256 + t;
        if (idx < F_IN * H_DIM) {
            int n = idx >> 9, k = idx & 511;
            w1t[idx] = f2bf(W1[k * H_DIM + n]);
        } else {
            int id2 = idx - F_IN * H_DIM;
            int n = id2 >> 8, k = id2 & 255;
            w2t[id2] = (n < C_DIM) ? f2bf(W2[k * C_DIM + n]) : (unsigned short)0;
        }
    } else {
        h1s[(size_t)N_NODES * H_DIM + t] = 0;        // zero row N (OOB gather target)
        if (t < C_PAD) h2b[(size_t)N_NODES * C_PAD + t] = 0;
    }
}

// ---------------- rowptr/cursor/dinv: self-sufficient per-block scan ----------------

__global__ __launch_bounds__(256) void rowptr_kernel(const int* __restrict__ cnt,
                                                     int* __restrict__ rowptr,
                                                     int* __restrict__ cursor,
                                                     float* __restrict__ dinv) {
    __shared__ int red[256];
    __shared__ int sc[256];
    const int t = threadIdx.x, j = blockIdx.x;
    int s = 0;
    for (int i = t; i < j * CHUNK; i += 256) s += cnt[i];
    red[t] = s;
    __syncthreads();
    for (int st = 128; st > 0; st >>= 1) {
        if (t < st) red[t] += red[t + st];
        __syncthreads();
    }
    const int boff = red[0];
    const int c = (t < CHUNK) ? cnt[j * CHUNK + t] : 0;
    sc[t] = c;
    __syncthreads();
    for (int st = 1; st < 256; st <<= 1) {       // Hillis-Steele inclusive
        int add = (t >= st) ? sc[t - st] : 0;
        __syncthreads();
        sc[t] += add;
        __syncthreads();
    }
    if (t < CHUNK) {
        int idx = j * CHUNK + t;
        int rp = boff + sc[t] - c;               // exclusive
        rowptr[idx] = rp;
        cursor[idx] = rp;
        dinv[idx] = rsqrtf((float)c + 1.0f);
    }
    if (j == NBLK - 1 && t == 0) rowptr[N_NODES] = E_EDGES;
}

// cursor pre-seeded with rowptr -> atomicAdd returns absolute slot; 4B record
__global__ void fill_kernel(const int* __restrict__ src, const int* __restrict__ dst,
                            int* __restrict__ cursor, int* __restrict__ esrc) {
    int e = blockIdx.x * blockDim.x + threadIdx.x;
    int s = src[e];
    int d = dst[e];
    esrc[atomicAdd(&cursor[d], 1)] = s;
}

// ---------------- gemm1: h1s[M,256] = bf16( dinv_row * (x[M,512] @ W1) ) ----------------
// 512 threads = 8 waves, tile 128(M) x 128(N), BK=32. Wave w: rows [w*16,w*16+16),
// 8 n-frags. grid = (2 col-halves, 157 row-blocks).

__global__ __launch_bounds__(512) void gemm1_kernel(const float* __restrict__ A,
                                                    const unsigned short* __restrict__ BT,
                                                    const float* __restrict__ dinv,
                                                    unsigned short* __restrict__ Cb) {
    __shared__ short As[128 * 40];
    __shared__ short Bs[128 * 40];
    const int tid = threadIdx.x;
    const int w = tid >> 6;
    const int lane = tid & 63;
    const int lq = lane >> 4;
    const int lm = lane & 15;
    const int row0 = blockIdx.y * 128;
    const int col0 = blockIdx.x * 128;
    const int sr = tid >> 2;        // 0..127
    const int sc = (tid & 3) * 8;   // 0,8,16,24

    floatx4 acc[8];
#pragma unroll
    for (int t = 0; t < 8; ++t) acc[t] = (floatx4){0.f, 0.f, 0.f, 0.f};

    for (int k0 = 0; k0 < F_IN; k0 += 32) {
        {
            const int gr = row0 + sr;
            short8 av = (short8){0,0,0,0,0,0,0,0};
            if (gr < N_NODES) {
                const float* p = A + (size_t)gr * F_IN + k0 + sc;
                float4 a0 = *(const float4*)p;
                float4 a1 = *(const float4*)(p + 4);
                av[0] = (short)f2bf(a0.x); av[1] = (short)f2bf(a0.y);
                av[2] = (short)f2bf(a0.z); av[3] = (short)f2bf(a0.w);
                av[4] = (short)f2bf(a1.x); av[5] = (short)f2bf(a1.y);
                av[6] = (short)f2bf(a1.z); av[7] = (short)f2bf(a1.w);
            }
            *(short8*)&As[sr * 40 + sc] = av;
            *(short8*)&Bs[sr * 40 + sc] =
                *(const short8*)&BT[(size_t)(col0 + sr) * F_IN + k0 + sc];
        }
        __syncthreads();
        short8 af = *(const short8*)&As[(w * 16 + lm) * 40 + lq * 8];
#pragma unroll
        for (int t = 0; t < 8; ++t) {
            short8 bf = *(const short8*)&Bs[(t * 16 + lm) * 40 + lq * 8];
            acc[t] = __builtin_amdgcn_mfma_f32_16x16x32_bf16(af, bf, acc[t], 0, 0, 0);
        }
        __syncthreads();
    }
    float dv[4];
#pragma unroll
    for (int r = 0; r < 4; ++r) {
        int row = row0 + w * 16 + lq * 4 + r;
        dv[r] = (row < N_NODES) ? dinv[row] : 0.f;
    }
#pragma unroll
    for (int t = 0; t < 8; ++t) {
#pragma unroll
        for (int r = 0; r < 4; ++r) {
            int row = row0 + w * 16 + lq * 4 + r;
            int col = col0 + t * 16 + lm;
            if (row < N_NODES) Cb[(size_t)row * H_DIM + col] = f2bf(acc[t][r] * dv[r]);
        }
    }
}

// ---------------- gemm2: h2b[M,64] = bf16( dinv_row * (hrb[M,256] @ W2) ) ----------------

__global__ __launch_bounds__(256) void gemm2_kernel(const unsigned short* __restrict__ Ab,
                                                    const unsigned short* __restrict__ BT,
                                                    const float* __restrict__ dinv,
                                                    unsigned short* __restrict__ Cb) {
    __shared__ short As[64 * 40];
    __shared__ short Bs[64 * 40];
    const int tid = threadIdx.x;
    const int w = tid >> 6;
    const int lane = tid & 63;
    const int lq = lane >> 4;
    const int lm = lane & 15;
    const int row0 = blockIdx.x * 64;
    const int sr = tid >> 2;
    const int sc = (tid & 3) * 8;

    floatx4 acc[4];
#pragma unroll
    for (int t = 0; t < 4; ++t) acc[t] = (floatx4){0.f, 0.f, 0.f, 0.f};

    for (int k0 = 0; k0 < H_DIM; k0 += 32) {
        {
            const int gr = row0 + sr;
            short8 av = (short8){0,0,0,0,0,0,0,0};
            if (gr < N_NODES)
                av = *(const short8*)&Ab[(size_t)gr * H_DIM + k0 + sc];
            *(short8*)&As[sr * 40 + sc] = av;
            *(short8*)&Bs[sr * 40 + sc] = *(const short8*)&BT[(size_t)sr * H_DIM + k0 + sc];
        }
        __syncthreads();
        short8 af = *(const short8*)&As[(w * 16 + lm) * 40 + lq * 8];
#pragma unroll
        for (int t = 0; t < 4; ++t) {
            short8 bf = *(const short8*)&Bs[(t * 16 + lm) * 40 + lq * 8];
            acc[t] = __builtin_amdgcn_mfma_f32_16x16x32_bf16(af, bf, acc[t], 0, 0, 0);
        }
        __syncthreads();
    }
    float dv[4];
#pragma unroll
    for (int r = 0; r < 4; ++r) {
        int row = row0 + w * 16 + lq * 4 + r;
        dv[r] = (row < N_NODES) ? dinv[row] : 0.f;
    }
#pragma unroll
    for (int t = 0; t < 4; ++t) {
#pragma unroll
        for (int r = 0; r < 4; ++r) {
            int row = row0 + w * 16 + lq * 4 + r;
            int col = t * 16 + lm;
            if (row < N_NODES) Cb[(size_t)row * C_PAD + col] = f2bf(acc[t][r] * dv[r]);
        }
    }
}

// ---------------- agg1: quarter-sliced plain-sum gather, 32 edges/iter ----------------
// Block b: quarter q=b&3 (XCD slicing), node i=(b>>2)*4+wave. Wave: 8 groups x
// 8 lanes; group g = edge slot; lane covers 8 features (16B) -> 128B line/edge.
// 4 independent gathers in flight per iter; esrc prefetched one iter ahead
// (prefetch values are never used as indices when OOB -> no slack init needed).

__global__ __launch_bounds__(256) void agg1_kernel(const unsigned short* __restrict__ h1s,
                                                   const int* __restrict__ rowptr,
                                                   const int* __restrict__ esrc,
                                                   const float* __restrict__ dinv,
                                                   const float* __restrict__ b1,
                                                   unsigned short* __restrict__ hrb) {
    const int b = blockIdx.x;
    const int q = b & 3;
    const int w = threadIdx.x >> 6;
    const int lane = threadIdx.x & 63;
    const int g = lane >> 3;          // edge slot 0..7
    const int lm = lane & 7;          // feature octet
    const int i = (b >> 2) * 4 + w;   // node
    const int fbase = q * 64 + lm * 8;
    const unsigned short* __restrict__ hp = h1s + fbase;
    const int rb = rowptr[i], re = rowptr[i + 1];
    float A0[8] = {0,0,0,0,0,0,0,0}, A1[8] = {0,0,0,0,0,0,0,0};
    int e0 = esrc[rb + g];
    int e1 = esrc[rb + 8 + g];
    int e2 = esrc[rb + 16 + g];
    int e3 = esrc[rb + 24 + g];
    for (int k = rb; k < re; k += 32) {
        int p0 = esrc[k + 32 + g];            // slack-padded (E+64), safe to read
        int p1 = esrc[k + 40 + g];
        int p2 = esrc[k + 48 + g];
        int p3 = esrc[k + 56 + g];
        int s0 = (k + g) < re ? e0 : N_NODES;
        int s1 = (k + 8 + g) < re ? e1 : N_NODES;
        int s2 = (k + 16 + g) < re ? e2 : N_NODES;
        int s3 = (k + 24 + g) < re ? e3 : N_NODES;
        uint4 v0 = *(const uint4*)(hp + ((size_t)s0 << 8));
        uint4 v1 = *(const uint4*)(hp + ((size_t)s1 << 8));
        uint4 v2 = *(const uint4*)(hp + ((size_t)s2 << 8));
        uint4 v3 = *(const uint4*)(hp + ((size_t)s3 << 8));
        ACC8(A0, v0); ACC8(A1, v1); ACC8(A0, v2); ACC8(A1, v3);
        e0 = p0; e1 = p1; e2 = p2; e3 = p3;
    }
    float r[8];
#pragma unroll
    for (int j = 0; j < 8; ++j) {
        float v = A0[j] + A1[j];
        v += __shfl_xor(v, 8, 64);
        v += __shfl_xor(v, 16, 64);
        v += __shfl_xor(v, 32, 64);
        r[j] = v;
    }
    if (lane < 8) {
        uint4 sv = *(const uint4*)(hp + ((size_t)i << 8));    // self (lm == lane)
        ACC8(r, sv);
        const float di = dinv[i];
        float4 bb0 = *(const float4*)&b1[fbase];
        float4 bb1 = *(const float4*)&b1[fbase + 4];
        float bv[8] = {bb0.x, bb0.y, bb0.z, bb0.w, bb1.x, bb1.y, bb1.z, bb1.w};
        float o[8];
#pragma unroll
        for (int j = 0; j < 8; ++j) o[j] = fmaxf(fmaf(di, r[j], bv[j]), 0.f);
        uint4 ov = make_uint4(pack2(o[0], o[1]), pack2(o[2], o[3]),
                              pack2(o[4], o[5]), pack2(o[6], o[7]));
        *(uint4*)&hrb[(size_t)i * H_DIM + fbase] = ov;
    }
}

// ---------------- agg2: wave/node plain-sum gather of h2b, 32 edges/iter ----------------

__global__ __launch_bounds__(256) void agg2_kernel(const unsigned short* __restrict__ h2b,
                                                   const int* __restrict__ rowptr,
                                                   const int* __restrict__ esrc,
                                                   const float* __restrict__ dinv,
                                                   const float* __restrict__ b2,
                                                   float* __restrict__ out) {
    const int i = (blockIdx.x * 256 + threadIdx.x) >> 6;   // node
    const int lane = threadIdx.x & 63;
    const int g = lane >> 3;          // edge slot 0..7
    const int lm = lane & 7;          // col octet
    const int c0 = lm * 8;
    const unsigned short* __restrict__ hp = h2b + c0;
    const int rb = rowptr[i], re = rowptr[i + 1];
    float A0[8] = {0,0,0,0,0,0,0,0}, A1[8] = {0,0,0,0,0,0,0,0};
    int e0 = esrc[rb + g];
    int e1 = esrc[rb + 8 + g];
    int e2 = esrc[rb + 16 + g];
    int e3 = esrc[rb + 24 + g];
    for (int k = rb; k < re; k += 32) {
        int p0 = esrc[k + 32 + g];
        int p1 = esrc[k + 40 + g];
        int p2 = esrc[k + 48 + g];
        int p3 = esrc[k + 56 + g];
        int s0 = (k + g) < re ? e0 : N_NODES;
        int s1 = (k + 8 + g) < re ? e1 : N_NODES;
        int s2 = (k + 16 + g) < re ? e2 : N_NODES;
        int s3 = (k + 24 + g) < re ? e3 : N_NODES;
        uint4 v0 = *(const uint4*)(hp + ((size_t)s0 << 6));
        uint4 v1 = *(const uint4*)(hp + ((size_t)s1 << 6));
        uint4 v2 = *(const uint4*)(hp + ((size_t)s2 << 6));
        uint4 v3 = *(const uint4*)(hp + ((size_t)s3 << 6));
        ACC8(A0, v0); ACC8(A1, v1); ACC8(A0, v2); ACC8(A1, v3);
        e0 = p0; e1 = p1; e2 = p2; e3 = p3;
    }
    float r[8];
#pragma unroll
    for (int j = 0; j < 8; ++j) {
        float v = A0[j] + A1[j];
        v += __shfl_xor(v, 8, 64);
        v += __shfl_xor(v, 16, 64);
        v += __shfl_xor(v, 32, 64);
        r[j] = v;
    }
    if (lane < 5) {                   // lm 0..4 -> cols 0..39
        uint4 sv = *(const uint4*)(hp + ((size_t)i << 6));
        ACC8(r, sv);
        const float di = dinv[i];
        float4 bb0 = *(const float4*)&b2[c0];
        float4 bb1 = *(const float4*)&b2[c0 + 4];
        float* op = &out[(size_t)i * C_DIM + c0];
        *(float4*)op = make_float4(fmaf(di, r[0], bb0.x), fmaf(di, r[1], bb0.y),
                                   fmaf(di, r[2], bb0.z), fmaf(di, r[3], bb0.w));
        *(float4*)(op + 4) = make_float4(fmaf(di, r[4], bb1.x), fmaf(di, r[5], bb1.y),
                                         fmaf(di, r[6], bb1.z), fmaf(di, r[7], bb1.w));
    }
}

// ---------------- launch ----------------

extern "C" void kernel_launch(void* const* d_in, const int* in_sizes, int n_in,
                              void* d_out, int out_size, void* d_ws, size_t ws_size,
                              hipStream_t stream) {
    const float* x   = (const float*)d_in[0];
    const int*   ei  = (const int*)d_in[1];
    const float* W1  = (const float*)d_in[2];
    const float* b1  = (const float*)d_in[3];
    const float* W2  = (const float*)d_in[4];
    const float* b2  = (const float*)d_in[5];
    float* out = (float*)d_out;

    const int* src = ei;            // edge_index[0]
    const int* dst = ei + E_EDGES;  // edge_index[1]

    // workspace layout, 128B-aligned. Total ~26.2 MB.
    char* ws = (char*)d_ws;
    int*            cnt    = (int*)(ws + 0);            //   80000 B
    float*          dinv   = (float*)(ws + 80128);      //   80000 B
    int*            rowptr = (int*)(ws + 160128);       //   80004 B
    int*            cursor = (int*)(ws + 240256);       //   80000 B
    int*            esrc   = (int*)(ws + 320256);       // (E+64)*4 = 2560256 B
    unsigned short* w1t    = (unsigned short*)(ws + 2880512);   //   262144 B
    unsigned short* w2t    = (unsigned short*)(ws + 3142656);   //    32768 B
    unsigned short* h1s    = (unsigned short*)(ws + 3175424);   // (N+1)*256*2 = 10240512 B
    unsigned short* hrb    = (unsigned short*)(ws + 13415936);  // N*256*2   = 10240000 B
    unsigned short* h2b    = (unsigned short*)(ws + 23655936);  // (N+1)*64*2 = 2560128 B

    hipMemsetAsync(cnt, 0, N_NODES * sizeof(int), stream);

    prep_kernel<<<EB + WB + 1, 256, 0, stream>>>(dst, cnt, W1, W2, w1t, w2t, h1s, h2b);
    rowptr_kernel<<<NBLK, 256, 0, stream>>>(cnt, rowptr, cursor, dinv);
    fill_kernel<<<EB, 256, 0, stream>>>(src, dst, cursor, esrc);

    dim3 g1(2, (N_NODES + 127) / 128);   // 2 x 157
    gemm1_kernel<<<g1, 512, 0, stream>>>(x, w1t, dinv, h1s);

    agg1_kernel<<<N_NODES, 256, 0, stream>>>(h1s, rowptr, esrc, dinv, b1, hrb);

    gemm2_kernel<<<(N_NODES + 63) / 64, 256, 0, stream>>>(hrb, w2t, dinv, h2b);

    agg2_kernel<<<N_NODES / 4, 256, 0, stream>>>(h2b, rowptr, esrc, dinv, b2, out);
}